// Round 2
// baseline (969.105 us; speedup 1.0000x reference)
//
#include <hip/hip_runtime.h>
#include <math.h>

#define Nn 15000
#define Ee 30000
#define TN 32   // node tile for k_gru2

// ---- workspace layout (float offsets) ----
// zero-init region (memset each call): [0 .. ZERO_END)
#define OFF_AGG   0          // [Nn*64]
#define OFF_DEG   960000     // [Nn]
#define OFF_HIST  975000     // [65] int
#define OFF_CUR   975072     // [65] int
#define OFF_HS    975144     // [64]
#define OFF_CS    975208     // [64]
#define OFF_RV    975272     // [64]
#define ZERO_END  975336
// written-before-read region:
#define OFF_OUT   975360     // [Nn*64]
#define OFF_DINV  1935360    // [Nn]
#define OFF_A     1950400    // [65*4096]
#define OFF_B     2216640    // [65*4096]
#define OFF_BP    2482880    // [64]
#define OFF_U     2482944    // [65*64]
#define OFF_V     2487104    // [65*64]
#define OFF_MC    2491264    // [1] int
#define OFF_PE    2491328    // [Ee] int
#define OFF_SSRC  2521328    // [Ee] int
#define OFF_SDST  2551328    // [Ee] int
#define OFF_SA    2581328    // [Ee] float
#define OFF_SP    2611328    // [Ee] int
#define OFF_WAT   2641328    // [64*256]
#define OFF_WBT   2657712    // [64*192]
#define OFF_GMAX  2670000    // [256]
#define OFF_GSUM  2670256    // [256]
#define OFF_GR    2670512    // [256*64]
#define WS_FLOATS 2686896

__device__ __forceinline__ float sigf(float x) { return 1.0f / (1.0f + expf(-x)); }
__device__ __forceinline__ float bcast(float v, int l) {
    return __int_as_float(__builtin_amdgcn_readlane(__float_as_int(v), l));
}

// out[n,o] = relu(x[n,:3] @ lin0_w[o,:3] + lin0_b[o])
__global__ void k_lin0(const float* __restrict__ x, const float* __restrict__ w,
                       const float* __restrict__ b, float* __restrict__ out) {
    int idx = blockIdx.x * 256 + threadIdx.x;
    if (idx >= Nn * 64) return;
    int n = idx >> 6, o = idx & 63;
    float v = b[o] + x[n*3+0]*w[o*3+0] + x[n*3+1]*w[o*3+1] + x[n*3+2]*w[o*3+2];
    out[idx] = fmaxf(v, 0.0f);
}

// he[e,k] = relu(a*w1[k]+b1[k]) piecewise-linear in scalar a: <=64 breakpoints.
__global__ void k_patterns(const float* __restrict__ e1w, const float* __restrict__ e1b,
                           float* __restrict__ bp, float* __restrict__ u,
                           float* __restrict__ v, int* __restrict__ mc) {
    __shared__ float t[64]; __shared__ int valid[64]; __shared__ float sbp[65]; __shared__ int cnt;
    int k = threadIdx.x;
    float w1 = e1w[k], b1 = e1b[k];
    float tv = 0.f; int va = 0;
    if (w1 != 0.f) { tv = -b1 / w1; va = (tv > 0.f && tv < 1.f) ? 1 : 0; }
    t[k] = tv; valid[k] = va;
    __syncthreads();
    if (va) {
        int rank = 0;
        for (int kk = 0; kk < 64; ++kk)
            if (valid[kk] && (t[kk] < tv || (t[kk] == tv && kk < k))) rank++;
        sbp[rank] = tv;
    }
    if (k == 0) { int c = 0; for (int kk = 0; kk < 64; ++kk) c += valid[kk]; cnt = c; *mc = c; }
    __syncthreads();
    int m = cnt;
    if (k < m) bp[k] = sbp[k];
    for (int j = 0; j <= m; ++j) {
        float lo = (j == 0) ? 0.f : sbp[j-1];
        float hi = (j == m) ? 1.f : sbp[j];
        float c = 0.5f * (lo + hi);
        int msk = (c * w1 + b1) > 0.f;
        u[j*64 + k] = msk ? w1 : 0.f;
        v[j*64 + k] = msk ? b1 : 0.f;
    }
}

// A_j[q] = sum_k u_j[k]*e2w[q,k];  B_j[q] = sum_k v_j[k]*e2w[q,k] + e2b[q]
__global__ void k_AB(const float* __restrict__ e2w, const float* __restrict__ e2b,
                     const float* __restrict__ u, const float* __restrict__ v,
                     const int* __restrict__ mc, float* __restrict__ A, float* __restrict__ B) {
    int j = blockIdx.x;
    if (j > *mc) return;
    __shared__ float su[64], sv[64];
    if (threadIdx.x < 64) { su[threadIdx.x] = u[j*64+threadIdx.x]; sv[threadIdx.x] = v[j*64+threadIdx.x]; }
    __syncthreads();
    for (int q = threadIdx.x; q < 4096; q += 256) {
        const float* row = e2w + q*64;
        float a = 0.f, b = 0.f;
        #pragma unroll 8
        for (int k = 0; k < 64; ++k) { float w = row[k]; a = fmaf(su[k], w, a); b = fmaf(sv[k], w, b); }
        A[j*4096 + q] = a;
        B[j*4096 + q] = b + e2b[q];
    }
}

// per-edge: degree atomic + pattern classify + pattern histogram
__global__ void k_eprep(const int* __restrict__ ei, const float* __restrict__ ea,
                        const float* __restrict__ bp, const int* __restrict__ mc,
                        float* __restrict__ deg, int* __restrict__ pe, int* __restrict__ hist) {
    int e = blockIdx.x * 256 + threadIdx.x;
    if (e >= Ee) return;
    atomicAdd(&deg[ei[Ee + e]], 1.0f);
    float a = ea[e];
    int m = *mc, p = 0;
    for (int j = 0; j < m; ++j) p += (bp[j] <= a) ? 1 : 0;
    pe[e] = p;
    atomicAdd(&hist[p], 1);
}

__global__ void k_scan_dinv(const float* __restrict__ deg, float* __restrict__ dinv,
                            const int* __restrict__ hist, int* __restrict__ cursor) {
    int n = blockIdx.x * 256 + threadIdx.x;
    if (n < Nn) dinv[n] = 1.0f / fmaxf(deg[n], 1.0f);
    if (blockIdx.x == 0 && threadIdx.x == 0) {
        int run = 0;
        for (int j = 0; j < 65; ++j) { cursor[j] = run; run += hist[j]; }
    }
}

__global__ void k_scatter(const int* __restrict__ ei, const float* __restrict__ ea,
                          const int* __restrict__ pe, int* __restrict__ cursor,
                          int* __restrict__ sS, int* __restrict__ sD,
                          float* __restrict__ sA, int* __restrict__ sP) {
    int e = blockIdx.x * 256 + threadIdx.x;
    if (e >= Ee) return;
    int p = pe[e];
    int pos = atomicAdd(&cursor[p], 1);
    sS[pos] = ei[e]; sD[pos] = ei[Ee + e]; sA[pos] = ea[e]; sP[pos] = p;
}

// transposed weight tables: wAt[i][0..63]=root_w[i][o]; wAt[i][64+g]=whh[g][i]; wBt[i][g]=wih[g][i]
__global__ void k_wt(const float* __restrict__ rootw, const float* __restrict__ whh,
                     const float* __restrict__ wih, float* __restrict__ wAt, float* __restrict__ wBt) {
    int idx = blockIdx.x * 256 + threadIdx.x;
    if (idx < 16384) {
        int i = idx >> 8, o = idx & 255;
        wAt[idx] = (o < 64) ? rootw[i*64 + o] : whh[(o-64)*64 + i];
    } else if (idx < 16384 + 12288) {
        int j = idx - 16384;
        int i = j / 192, g = j % 192;
        wBt[j] = wih[g*64 + i];
    }
}

// pattern-sorted edge kernel: wave per edge-chunk, pattern A,B columns cached in VGPRs.
__global__ __launch_bounds__(256) void k_edge2(
        const int* __restrict__ sS, const int* __restrict__ sD,
        const float* __restrict__ sA, const int* __restrict__ sP,
        const float* __restrict__ out, const float* __restrict__ A,
        const float* __restrict__ B, const float* __restrict__ dinv,
        float* __restrict__ agg) {
    int tid = threadIdx.x, lane = tid & 63;
    int wid = (blockIdx.x * 256 + tid) >> 6;       // 0..2047
    const int CH = (Ee + 2047) / 2048;
    int e0 = wid * CH;
    int e1 = e0 + CH; if (e1 > Ee) e1 = Ee;
    float Ar[64], Br[64];
    int curp = -1;
    for (int e = e0; e < e1; ++e) {
        int p = sP[e];
        if (p != curp) {
            curp = p;
            const float* Ap = A + p*4096 + lane;
            const float* Bp = B + p*4096 + lane;
            #pragma unroll
            for (int i = 0; i < 64; ++i) { Ar[i] = Ap[i*64]; Br[i] = Bp[i*64]; }
        }
        int src = sS[e], dst = sD[e];
        float a = sA[e];
        float hv = out[src*64 + lane];
        float acc = 0.f;
        #pragma unroll
        for (int i = 0; i < 64; ++i) {
            float hi = bcast(hv, i);
            acc = fmaf(hi, fmaf(a, Ar[i], Br[i]), acc);
        }
        acc *= dinv[dst];
        atomicAdd(&agg[dst*64 + lane], acc);
    }
}

// fused NNConv-root + full GRU, register-blocked GEMM.
// 4 waves per 32-node tile: phase1 w0:root->m, w1..3: gh gates; phase2 w1..3: gi gates; w3 combines.
__global__ __launch_bounds__(256) void k_gru2(
        float* __restrict__ out, float* __restrict__ agg,
        const float* __restrict__ wAt, const float* __restrict__ wBt,
        const float* __restrict__ convb, const float* __restrict__ gbih,
        const float* __restrict__ gbhh) {
    __shared__ __align__(16) float hT[64*36];   // hT[i*36+n] = h[n][i]
    __shared__ __align__(16) float mT[64*36];
    __shared__ float cb_r[TN*64];
    __shared__ float cb_z[TN*64];
    int tid = threadIdx.x, lane = tid & 63, w = tid >> 6;
    int n0 = blockIdx.x * TN;

    // stage h tile transposed
    #pragma unroll
    for (int p = 0; p < 8; ++p) {
        int idx = p*256 + tid;
        int n = idx >> 6, i = idx & 63;
        int gn = n0 + n;
        hT[i*36 + n] = (gn < Nn) ? out[gn*64 + i] : 0.f;
    }
    __syncthreads();

    // phase 1: acc[n] = bias + sum_i h[n][i] * wAt[i][w*64+lane]
    float acc[TN];
    float bias = (w == 0) ? 0.f : gbhh[(w-1)*64 + lane];
    #pragma unroll
    for (int n = 0; n < TN; ++n) acc[n] = bias;
    const float* wcolA = wAt + w*64 + lane;
    #pragma unroll 4
    for (int i = 0; i < 64; ++i) {
        float wv = wcolA[i*256];
        const float4* h4 = (const float4*)(hT + i*36);
        #pragma unroll
        for (int q = 0; q < 8; ++q) {
            float4 hv = h4[q];
            acc[q*4+0] = fmaf(hv.x, wv, acc[q*4+0]);
            acc[q*4+1] = fmaf(hv.y, wv, acc[q*4+1]);
            acc[q*4+2] = fmaf(hv.z, wv, acc[q*4+2]);
            acc[q*4+3] = fmaf(hv.w, wv, acc[q*4+3]);
        }
    }
    // epilogue: w0 builds m (consumes+zeros agg), writes mT; w1..3 keep gh in acc
    if (w == 0) {
        float cbv = convb[lane];
        #pragma unroll
        for (int n = 0; n < TN; ++n) {
            int gn = n0 + n;
            float mval = 0.f;
            if (gn < Nn) {
                float av = agg[gn*64 + lane];
                agg[gn*64 + lane] = 0.f;
                mval = fmaxf(acc[n] + av + cbv, 0.f);
            }
            mT[lane*36 + n] = mval;
        }
    }
    __syncthreads();

    // phase 2: w1..3: acc2[n] = bih + sum_i m[n][i] * wBt[i][(w-1)*64+lane]
    float acc2[TN];
    if (w > 0) {
        float b2 = gbih[(w-1)*64 + lane];
        #pragma unroll
        for (int n = 0; n < TN; ++n) acc2[n] = b2;
        const float* wcolB = wBt + (w-1)*64 + lane;
        #pragma unroll 4
        for (int i = 0; i < 64; ++i) {
            float wv = wcolB[i*192];
            const float4* m4 = (const float4*)(mT + i*36);
            #pragma unroll
            for (int q = 0; q < 8; ++q) {
                float4 mv = m4[q];
                acc2[q*4+0] = fmaf(mv.x, wv, acc2[q*4+0]);
                acc2[q*4+1] = fmaf(mv.y, wv, acc2[q*4+1]);
                acc2[q*4+2] = fmaf(mv.z, wv, acc2[q*4+2]);
                acc2[q*4+3] = fmaf(mv.w, wv, acc2[q*4+3]);
            }
        }
        if (w == 1) {
            #pragma unroll
            for (int n = 0; n < TN; ++n) cb_r[n*64 + lane] = sigf(acc2[n] + acc[n]);
        } else if (w == 2) {
            #pragma unroll
            for (int n = 0; n < TN; ++n) cb_z[n*64 + lane] = sigf(acc2[n] + acc[n]);
        }
    }
    __syncthreads();

    // phase 3: w3 combines (holds gi_n in acc2, gh_n in acc)
    if (w == 3) {
        #pragma unroll
        for (int n = 0; n < TN; ++n) {
            int gn = n0 + n;
            if (gn < Nn) {
                float r  = cb_r[n*64 + lane];
                float z  = cb_z[n*64 + lane];
                float nn = tanhf(fmaf(r, acc[n], acc2[n]));
                float h  = hT[lane*36 + n];
                out[gn*64 + lane] = (1.f - z)*nn + z*h;
            }
        }
    }
}

// Set2Set: one-pass online-softmax partials per block (logits+max+sum+weighted sum fused)
__global__ __launch_bounds__(256) void k_part(const float* __restrict__ out,
        const float* __restrict__ hs, float* __restrict__ gmax,
        float* __restrict__ gsum, float* __restrict__ gr) {
    __shared__ float sm_m[4], sm_z[4], sm_r[4][64];
    int tid = threadIdx.x, lane = tid & 63, w = tid >> 6;
    float hsv = hs[lane];
    float m = -3.4e38f, Z = 0.f, racc = 0.f;
    for (int n = blockIdx.x*4 + w; n < Nn; n += 1024) {
        float ov = out[n*64 + lane];
        float p = ov * hsv;
        #pragma unroll
        for (int off = 32; off > 0; off >>= 1) p += __shfl_xor(p, off, 64);
        float mn = fmaxf(m, p);
        float sc = expf(m - mn);
        float t  = expf(p - mn);
        Z = fmaf(Z, sc, t);
        racc = fmaf(racc, sc, t*ov);
        m = mn;
    }
    if (lane == 0) { sm_m[w] = m; sm_z[w] = Z; }
    sm_r[w][lane] = racc;
    __syncthreads();
    if (w == 0) {
        float M = fmaxf(fmaxf(sm_m[0], sm_m[1]), fmaxf(sm_m[2], sm_m[3]));
        float Zb = 0.f, rb = 0.f;
        #pragma unroll
        for (int j = 0; j < 4; ++j) {
            float e = expf(sm_m[j] - M);
            Zb = fmaf(sm_z[j], e, Zb);
            rb = fmaf(sm_r[j][lane], e, rb);
        }
        gr[blockIdx.x*64 + lane] = rb;
        if (lane == 0) { gmax[blockIdx.x] = M; gsum[blockIdx.x] = Zb; }
    }
}

// finalize partials -> rv, then Set2Set LSTM step
__global__ __launch_bounds__(256) void k_lstm2(const float* __restrict__ wih,
        const float* __restrict__ whh, const float* __restrict__ bih,
        const float* __restrict__ bhh, float* __restrict__ hs, float* __restrict__ cs,
        float* __restrict__ rv, const float* __restrict__ gmax,
        const float* __restrict__ gsum, const float* __restrict__ gr, int it) {
    __shared__ float red[256], shs[64], srv[64], sg[256];
    int tid = threadIdx.x, lane = tid & 63, w = tid >> 6;
    if (it > 0) {
        float gm = gmax[tid];
        red[tid] = gm; __syncthreads();
        for (int s = 128; s > 0; s >>= 1) { if (tid < s) red[tid] = fmaxf(red[tid], red[tid+s]); __syncthreads(); }
        float M = red[0]; __syncthreads();
        red[tid] = gsum[tid] * expf(gm - M); __syncthreads();
        for (int s = 128; s > 0; s >>= 1) { if (tid < s) red[tid] += red[tid+s]; __syncthreads(); }
        float Z = red[0]; __syncthreads();
        float racc = 0.f;
        for (int b = w; b < 256; b += 4) racc = fmaf(gr[b*64 + lane], expf(gmax[b] - M), racc);
        red[tid] = racc; __syncthreads();
        if (w == 0) rv[lane] = (red[lane] + red[64+lane] + red[128+lane] + red[192+lane]) / Z;
        __syncthreads();
    }
    if (tid < 64) { shs[tid] = hs[tid]; srv[tid] = rv[tid]; }
    __syncthreads();
    const float* wi = wih + tid*128;
    const float* wh = whh + tid*64;
    float g = bih[tid] + bhh[tid];
    #pragma unroll 8
    for (int i = 0; i < 64; ++i) g += shs[i]*(wi[i] + wh[i]) + srv[i]*wi[64+i];
    sg[tid] = g; __syncthreads();
    if (tid < 64) {
        float ii = sigf(sg[tid]), ff = sigf(sg[64+tid]);
        float gg = tanhf(sg[128+tid]), oo = sigf(sg[192+tid]);
        float c2 = ff*cs[tid] + ii*gg;
        cs[tid] = c2; hs[tid] = oo*tanhf(c2);
    }
}

// final: finalize rv, mem-LSTM (h=c=0), lin1, lin3 -> dout = [v, hx(64), cx(64)]
__global__ __launch_bounds__(256) void k_final2(const float* __restrict__ mwih,
        const float* __restrict__ mbih, const float* __restrict__ mbhh,
        const float* __restrict__ hs, float* __restrict__ rv,
        const float* __restrict__ gmax, const float* __restrict__ gsum,
        const float* __restrict__ gr,
        const float* __restrict__ l1w, const float* __restrict__ l1b,
        const float* __restrict__ l3w, const float* __restrict__ l3b,
        float* __restrict__ dout) {
    __shared__ float red[256], shs[64], srv[64], sg[256], shx[64], so[64];
    int tid = threadIdx.x, lane = tid & 63, w = tid >> 6;
    {
        float gm = gmax[tid];
        red[tid] = gm; __syncthreads();
        for (int s = 128; s > 0; s >>= 1) { if (tid < s) red[tid] = fmaxf(red[tid], red[tid+s]); __syncthreads(); }
        float M = red[0]; __syncthreads();
        red[tid] = gsum[tid] * expf(gm - M); __syncthreads();
        for (int s = 128; s > 0; s >>= 1) { if (tid < s) red[tid] += red[tid+s]; __syncthreads(); }
        float Z = red[0]; __syncthreads();
        float racc = 0.f;
        for (int b = w; b < 256; b += 4) racc = fmaf(gr[b*64 + lane], expf(gmax[b] - M), racc);
        red[tid] = racc; __syncthreads();
        if (w == 0) rv[lane] = (red[lane] + red[64+lane] + red[128+lane] + red[192+lane]) / Z;
        __syncthreads();
    }
    if (tid < 64) { shs[tid] = hs[tid]; srv[tid] = rv[tid]; }
    __syncthreads();
    const float* wi = mwih + tid*128;
    float g = mbih[tid] + mbhh[tid];
    #pragma unroll 8
    for (int i = 0; i < 64; ++i) g += shs[i]*wi[i] + srv[i]*wi[64+i];
    sg[tid] = g; __syncthreads();
    if (tid < 64) {
        float ii = sigf(sg[tid]);
        float gg = tanhf(sg[128+tid]);
        float oo = sigf(sg[192+tid]);
        float c2 = ii * gg;
        float hx = oo * tanhf(c2);
        shx[tid] = hx;
        dout[1 + tid] = hx;
        dout[65 + tid] = c2;
    }
    __syncthreads();
    if (tid < 64) {
        float a = l1b[tid];
        const float* wr = l1w + tid*64;
        #pragma unroll 8
        for (int i = 0; i < 64; ++i) a = fmaf(shx[i], wr[i], a);
        so[tid] = fmaxf(a, 0.f);
    }
    __syncthreads();
    if (tid == 0) {
        float v = l3b[0];
        for (int i = 0; i < 64; ++i) v = fmaf(so[i], l3w[i], v);
        dout[0] = v;
    }
}

extern "C" void kernel_launch(void* const* d_in, const int* in_sizes, int n_in,
                              void* d_out, int out_size, void* d_ws, size_t ws_size,
                              hipStream_t stream) {
    const float* x    = (const float*)d_in[0];
    const int*   ei   = (const int*)  d_in[1];
    const float* ea   = (const float*)d_in[2];
    const float* l0w  = (const float*)d_in[3];
    const float* l0b  = (const float*)d_in[4];
    const float* e1w  = (const float*)d_in[5];
    const float* e1b  = (const float*)d_in[6];
    const float* e2w  = (const float*)d_in[7];
    const float* e2b  = (const float*)d_in[8];
    const float* rootw= (const float*)d_in[9];
    const float* convb= (const float*)d_in[10];
    const float* gwih = (const float*)d_in[11];
    const float* gwhh = (const float*)d_in[12];
    const float* gbih = (const float*)d_in[13];
    const float* gbhh = (const float*)d_in[14];
    const float* swih = (const float*)d_in[15];
    const float* swhh = (const float*)d_in[16];
    const float* sbih = (const float*)d_in[17];
    const float* sbhh = (const float*)d_in[18];
    const float* mwih = (const float*)d_in[19];
    const float* mbih = (const float*)d_in[21];
    const float* mbhh = (const float*)d_in[22];
    const float* l1w  = (const float*)d_in[23];
    const float* l1b  = (const float*)d_in[24];
    const float* l3w  = (const float*)d_in[25];
    const float* l3b  = (const float*)d_in[26];

    float* ws   = (float*)d_ws;
    float* dout = (float*)d_out;
    if (ws_size < (size_t)WS_FLOATS * sizeof(float)) return;

    float* agg  = ws + OFF_AGG;
    float* deg  = ws + OFF_DEG;
    int*   hist = (int*)(ws + OFF_HIST);
    int*   cur  = (int*)(ws + OFF_CUR);
    float* hs   = ws + OFF_HS;
    float* cs   = ws + OFF_CS;
    float* rv   = ws + OFF_RV;
    float* out  = ws + OFF_OUT;
    float* dinv = ws + OFF_DINV;
    float* Abuf = ws + OFF_A;
    float* Bbuf = ws + OFF_B;
    float* bp   = ws + OFF_BP;
    float* ubuf = ws + OFF_U;
    float* vbuf = ws + OFF_V;
    int*   mc   = (int*)(ws + OFF_MC);
    int*   pe   = (int*)(ws + OFF_PE);
    int*   sS   = (int*)(ws + OFF_SSRC);
    int*   sD   = (int*)(ws + OFF_SDST);
    float* sA   = ws + OFF_SA;
    int*   sP   = (int*)(ws + OFF_SP);
    float* wAt  = ws + OFF_WAT;
    float* wBt  = ws + OFF_WBT;
    float* gmax = ws + OFF_GMAX;
    float* gsum = ws + OFF_GSUM;
    float* gr   = ws + OFF_GR;

    hipMemsetAsync(d_ws, 0, (size_t)ZERO_END * sizeof(float), stream);

    k_lin0    <<<(Nn*64 + 255)/256, 256, 0, stream>>>(x, l0w, l0b, out);
    k_patterns<<<1, 64, 0, stream>>>(e1w, e1b, bp, ubuf, vbuf, mc);
    k_AB      <<<65, 256, 0, stream>>>(e2w, e2b, ubuf, vbuf, mc, Abuf, Bbuf);
    k_eprep   <<<(Ee + 255)/256, 256, 0, stream>>>(ei, ea, bp, mc, deg, pe, hist);
    k_scan_dinv<<<(Nn + 255)/256, 256, 0, stream>>>(deg, dinv, hist, cur);
    k_scatter <<<(Ee + 255)/256, 256, 0, stream>>>(ei, ea, pe, cur, sS, sD, sA, sP);
    k_wt      <<<(16384 + 12288 + 255)/256, 256, 0, stream>>>(rootw, gwhh, gwih, wAt, wBt);

    for (int s = 0; s < 6; ++s) {
        k_edge2<<<512, 256, 0, stream>>>(sS, sD, sA, sP, out, Abuf, Bbuf, dinv, agg);
        k_gru2 <<<(Nn + TN - 1)/TN, 256, 0, stream>>>(out, agg, wAt, wBt, convb, gbih, gbhh);
    }

    for (int it = 0; it < 6; ++it) {
        k_lstm2<<<1, 256, 0, stream>>>(swih, swhh, sbih, sbhh, hs, cs, rv, gmax, gsum, gr, it);
        k_part <<<256, 256, 0, stream>>>(out, hs, gmax, gsum, gr);
    }

    k_final2<<<1, 256, 0, stream>>>(mwih, mbih, mbhh, hs, rv, gmax, gsum, gr,
                                    l1w, l1b, l3w, l3b, dout);
}

// Round 3
// 795.971 us; speedup vs baseline: 1.2175x; 1.2175x over previous
//
#include <hip/hip_runtime.h>
#include <math.h>

#define Nn 15000
#define Ee 30000
#define TN 32      // node tile for k_gru2
#define NB_E 118   // ceil(Ee/256)
#define EB 768     // k_edge3 blocks

// ---- workspace layout (float offsets) ----
// zero region (memset each call):
#define OFF_AGG   0          // [Nn*64]
#define OFF_DEG   960000     // [Nn]
#define ZERO_END  975000
// written-before-read region:
#define OFF_OUT   975008     // [Nn*64]
#define OFF_DINV  1935008    // [Nn]
#define OFF_AT    1950016    // [65*4096] transposed: At[p][o*64+i]
#define OFF_BT    2216256    // [65*4096]
#define OFF_BP    2482496    // [64]
#define OFF_U     2482560    // [65*64]
#define OFF_V     2486720    // [65*64]
#define OFF_MC    2490880    // [1] int
#define OFF_PE    2490884    // [Ee] int
#define OFF_BH    2520884    // [NB_E*65] int per-block hist
#define OFF_BC    2528554    // [NB_E*65] int per-block cursors
#define OFF_SS    2536224    // [Ee] int
#define OFF_SD    2566224    // [Ee] int
#define OFF_SA    2596224    // [Ee] float
#define OFF_SP    2626224    // [Ee] int
#define OFF_WAT   2656224    // [64*256]
#define OFF_WBT   2672608    // [64*192]
#define OFF_GMA   2684896    // [256]
#define OFF_GSA   2685152    // [256]
#define OFF_GRA   2685408    // [256*64]
#define OFF_GMB   2701792    // [256]
#define OFF_GSB   2702048    // [256]
#define OFF_GRB   2702304    // [256*64]
#define OFF_HS    2718688    // [64]
#define OFF_CS    2718752    // [64]
#define WS_FLOATS 2718816

__device__ __forceinline__ float sigf(float x) { return 1.0f / (1.0f + expf(-x)); }
__device__ __forceinline__ float bcast(float v, int l) {
    return __int_as_float(__builtin_amdgcn_readlane(__float_as_int(v), l));
}

__global__ void k_lin0(const float* __restrict__ x, const float* __restrict__ w,
                       const float* __restrict__ b, float* __restrict__ out) {
    int idx = blockIdx.x * 256 + threadIdx.x;
    if (idx >= Nn * 64) return;
    int n = idx >> 6, o = idx & 63;
    float v = b[o] + x[n*3+0]*w[o*3+0] + x[n*3+1]*w[o*3+1] + x[n*3+2]*w[o*3+2];
    out[idx] = fmaxf(v, 0.0f);
}

// he[e,k] = relu(a*w1[k]+b1[k]) piecewise-linear in scalar a: <=64 breakpoints.
__global__ void k_patterns(const float* __restrict__ e1w, const float* __restrict__ e1b,
                           float* __restrict__ bp, float* __restrict__ u,
                           float* __restrict__ v, int* __restrict__ mc) {
    __shared__ float t[64]; __shared__ int valid[64]; __shared__ float sbp[65]; __shared__ int cnt;
    int k = threadIdx.x;
    float w1 = e1w[k], b1 = e1b[k];
    float tv = 0.f; int va = 0;
    if (w1 != 0.f) { tv = -b1 / w1; va = (tv > 0.f && tv < 1.f) ? 1 : 0; }
    t[k] = tv; valid[k] = va;
    __syncthreads();
    if (va) {
        int rank = 0;
        for (int kk = 0; kk < 64; ++kk)
            if (valid[kk] && (t[kk] < tv || (t[kk] == tv && kk < k))) rank++;
        sbp[rank] = tv;
    }
    if (k == 0) { int c = 0; for (int kk = 0; kk < 64; ++kk) c += valid[kk]; cnt = c; *mc = c; }
    __syncthreads();
    int m = cnt;
    if (k < m) bp[k] = sbp[k];
    for (int j = 0; j <= m; ++j) {
        float lo = (j == 0) ? 0.f : sbp[j-1];
        float hi = (j == m) ? 1.f : sbp[j];
        float c = 0.5f * (lo + hi);
        int msk = (c * w1 + b1) > 0.f;
        u[j*64 + k] = msk ? w1 : 0.f;
        v[j*64 + k] = msk ? b1 : 0.f;
    }
}

// transposed outputs: At[j][o*64+i] = sum_k u_j[k]*e2w[(i*64+o)*64+k]; Bt likewise + e2b
__global__ void k_AB(const float* __restrict__ e2w, const float* __restrict__ e2b,
                     const float* __restrict__ u, const float* __restrict__ v,
                     const int* __restrict__ mc, float* __restrict__ At, float* __restrict__ Bt) {
    int j = blockIdx.x;
    if (j > *mc) return;
    __shared__ float su[64], sv[64];
    if (threadIdx.x < 64) { su[threadIdx.x] = u[j*64+threadIdx.x]; sv[threadIdx.x] = v[j*64+threadIdx.x]; }
    __syncthreads();
    for (int q = threadIdx.x; q < 4096; q += 256) {
        int i = q >> 6, o = q & 63;
        const float* row = e2w + q*64;
        float a = 0.f, b = 0.f;
        #pragma unroll 8
        for (int k = 0; k < 64; ++k) { float w = row[k]; a = fmaf(su[k], w, a); b = fmaf(sv[k], w, b); }
        At[j*4096 + o*64 + i] = a;
        Bt[j*4096 + o*64 + i] = b + e2b[q];
    }
}

// per-block LDS histogram (no global hist atomics) + deg + classify
__global__ void k_eprep2(const int* __restrict__ ei, const float* __restrict__ ea,
                         const float* __restrict__ bp, const int* __restrict__ mc,
                         float* __restrict__ deg, int* __restrict__ pe, int* __restrict__ bh) {
    __shared__ int lh[65];
    int tid = threadIdx.x;
    if (tid < 65) lh[tid] = 0;
    __syncthreads();
    int e = blockIdx.x * 256 + tid;
    if (e < Ee) {
        atomicAdd(&deg[ei[Ee + e]], 1.0f);
        float a = ea[e];
        int m = *mc, p = 0;
        for (int j = 0; j < m; ++j) p += (bp[j] <= a) ? 1 : 0;
        pe[e] = p;
        atomicAdd(&lh[p], 1);
    }
    __syncthreads();
    if (tid < 65) bh[blockIdx.x*65 + tid] = lh[tid];
}

// blocks 0..58: dinv; block 59: two-level scan -> per-block per-bin cursors
__global__ void k_scan2(const float* __restrict__ deg, float* __restrict__ dinv,
                        const int* __restrict__ bh, int* __restrict__ bc) {
    int tid = threadIdx.x;
    if (blockIdx.x < 59) {
        int n = blockIdx.x * 256 + tid;
        if (n < Nn) dinv[n] = 1.0f / fmaxf(deg[n], 1.0f);
        return;
    }
    __shared__ int stot[65]; __shared__ int sbase[65];
    if (tid < 65) {
        int t = 0;
        for (int b = 0; b < NB_E; ++b) t += bh[b*65 + tid];
        stot[tid] = t;
    }
    __syncthreads();
    if (tid == 0) {
        int run = 0;
        for (int j = 0; j < 65; ++j) { sbase[j] = run; run += stot[j]; }
    }
    __syncthreads();
    if (tid < 65) {
        int run = sbase[tid];
        for (int b = 0; b < NB_E; ++b) { bc[b*65 + tid] = run; run += bh[b*65 + tid]; }
    }
}

// scatter using per-block LDS cursors (LDS atomics only)
__global__ void k_scatter2(const int* __restrict__ ei, const float* __restrict__ ea,
                           const int* __restrict__ pe, const int* __restrict__ bc,
                           int* __restrict__ sS, int* __restrict__ sD,
                           float* __restrict__ sA, int* __restrict__ sP) {
    __shared__ int cur[65];
    int tid = threadIdx.x;
    if (tid < 65) cur[tid] = bc[blockIdx.x*65 + tid];
    __syncthreads();
    int e = blockIdx.x * 256 + tid;
    if (e >= Ee) return;
    int p = pe[e];
    int pos = atomicAdd(&cur[p], 1);
    sS[pos] = ei[e]; sD[pos] = ei[Ee + e]; sA[pos] = ea[e]; sP[pos] = p;
}

// transposed weight tables: wAt[i][0..63]=root_w[i][o]; wAt[i][64+g]=whh[g][i]; wBt[i][g]=wih[g][i]
__global__ void k_wt(const float* __restrict__ rootw, const float* __restrict__ whh,
                     const float* __restrict__ wih, float* __restrict__ wAt, float* __restrict__ wBt) {
    int idx = blockIdx.x * 256 + threadIdx.x;
    if (idx < 16384) {
        int i = idx >> 8, o = idx & 255;
        wAt[idx] = (o < 64) ? rootw[i*64 + o] : whh[(o-64)*64 + i];
    } else if (idx < 16384 + 12288) {
        int j = idx - 16384;
        int i = j / 192, g = j % 192;
        wBt[j] = wih[g*64 + i];
    }
}

// pattern-sorted edges, VGPR-cached pattern columns (float4 reload from transposed At/Bt)
__global__ __launch_bounds__(256) void k_edge3(
        const int* __restrict__ sS, const int* __restrict__ sD,
        const float* __restrict__ sA, const int* __restrict__ sP,
        const float* __restrict__ out, const float* __restrict__ At,
        const float* __restrict__ Bt, const float* __restrict__ dinv,
        float* __restrict__ agg) {
    int tid = threadIdx.x, lane = tid & 63;
    int wid = (blockIdx.x * 256 + tid) >> 6;       // 0..EB*4-1
    const int NW = EB * 4;
    const int CH = (Ee + NW - 1) / NW;
    int e0 = wid * CH;
    int e1 = e0 + CH; if (e1 > Ee) e1 = Ee;
    float Ar[64], Br[64];
    int curp = -1;
    for (int e = e0; e < e1; ++e) {
        int p = sP[e];
        if (p != curp) {
            curp = p;
            const float4* Ap4 = (const float4*)(At + p*4096 + lane*64);
            const float4* Bp4 = (const float4*)(Bt + p*4096 + lane*64);
            #pragma unroll
            for (int q = 0; q < 16; ++q) {
                float4 av = Ap4[q], bv = Bp4[q];
                Ar[q*4+0]=av.x; Ar[q*4+1]=av.y; Ar[q*4+2]=av.z; Ar[q*4+3]=av.w;
                Br[q*4+0]=bv.x; Br[q*4+1]=bv.y; Br[q*4+2]=bv.z; Br[q*4+3]=bv.w;
            }
        }
        int src = sS[e], dst = sD[e];
        float a = sA[e];
        float hv = out[src*64 + lane];
        float acc0 = 0.f, acc1 = 0.f;
        #pragma unroll
        for (int i = 0; i < 64; i += 2) {
            float h0 = bcast(hv, i);
            float h1 = bcast(hv, i+1);
            acc0 = fmaf(h0, fmaf(a, Ar[i],   Br[i]),   acc0);
            acc1 = fmaf(h1, fmaf(a, Ar[i+1], Br[i+1]), acc1);
        }
        float acc = (acc0 + acc1) * dinv[dst];
        atomicAdd(&agg[dst*64 + lane], acc);
    }
}

// fused NNConv-root + full GRU, register-blocked GEMM; re-zeros agg.
__global__ __launch_bounds__(256) void k_gru2(
        float* __restrict__ out, float* __restrict__ agg,
        const float* __restrict__ wAt, const float* __restrict__ wBt,
        const float* __restrict__ convb, const float* __restrict__ gbih,
        const float* __restrict__ gbhh) {
    __shared__ __align__(16) float hT[64*36];
    __shared__ __align__(16) float mT[64*36];
    __shared__ float cb_r[TN*64];
    __shared__ float cb_z[TN*64];
    int tid = threadIdx.x, lane = tid & 63, w = tid >> 6;
    int n0 = blockIdx.x * TN;

    #pragma unroll
    for (int p = 0; p < 8; ++p) {
        int idx = p*256 + tid;
        int n = idx >> 6, i = idx & 63;
        int gn = n0 + n;
        hT[i*36 + n] = (gn < Nn) ? out[gn*64 + i] : 0.f;
    }
    __syncthreads();

    float acc[TN];
    float bias = (w == 0) ? 0.f : gbhh[(w-1)*64 + lane];
    #pragma unroll
    for (int n = 0; n < TN; ++n) acc[n] = bias;
    const float* wcolA = wAt + w*64 + lane;
    #pragma unroll 4
    for (int i = 0; i < 64; ++i) {
        float wv = wcolA[i*256];
        const float4* h4 = (const float4*)(hT + i*36);
        #pragma unroll
        for (int q = 0; q < 8; ++q) {
            float4 hv = h4[q];
            acc[q*4+0] = fmaf(hv.x, wv, acc[q*4+0]);
            acc[q*4+1] = fmaf(hv.y, wv, acc[q*4+1]);
            acc[q*4+2] = fmaf(hv.z, wv, acc[q*4+2]);
            acc[q*4+3] = fmaf(hv.w, wv, acc[q*4+3]);
        }
    }
    if (w == 0) {
        float cbv = convb[lane];
        #pragma unroll
        for (int n = 0; n < TN; ++n) {
            int gn = n0 + n;
            float mval = 0.f;
            if (gn < Nn) {
                float av = agg[gn*64 + lane];
                agg[gn*64 + lane] = 0.f;
                mval = fmaxf(acc[n] + av + cbv, 0.f);
            }
            mT[lane*36 + n] = mval;
        }
    }
    __syncthreads();

    float acc2[TN];
    if (w > 0) {
        float b2 = gbih[(w-1)*64 + lane];
        #pragma unroll
        for (int n = 0; n < TN; ++n) acc2[n] = b2;
        const float* wcolB = wBt + (w-1)*64 + lane;
        #pragma unroll 4
        for (int i = 0; i < 64; ++i) {
            float wv = wcolB[i*192];
            const float4* m4 = (const float4*)(mT + i*36);
            #pragma unroll
            for (int q = 0; q < 8; ++q) {
                float4 mv = m4[q];
                acc2[q*4+0] = fmaf(mv.x, wv, acc2[q*4+0]);
                acc2[q*4+1] = fmaf(mv.y, wv, acc2[q*4+1]);
                acc2[q*4+2] = fmaf(mv.z, wv, acc2[q*4+2]);
                acc2[q*4+3] = fmaf(mv.w, wv, acc2[q*4+3]);
            }
        }
        if (w == 1) {
            #pragma unroll
            for (int n = 0; n < TN; ++n) cb_r[n*64 + lane] = sigf(acc2[n] + acc[n]);
        } else if (w == 2) {
            #pragma unroll
            for (int n = 0; n < TN; ++n) cb_z[n*64 + lane] = sigf(acc2[n] + acc[n]);
        }
    }
    __syncthreads();

    if (w == 3) {
        #pragma unroll
        for (int n = 0; n < TN; ++n) {
            int gn = n0 + n;
            if (gn < Nn) {
                float r  = cb_r[n*64 + lane];
                float z  = cb_z[n*64 + lane];
                float nn = tanhf(fmaf(r, acc[n], acc2[n]));
                float h  = hT[lane*36 + n];
                out[gn*64 + lane] = (1.f - z)*nn + z*h;
            }
        }
    }
}

// one launch per Set2Set iteration: every block redundantly finalizes prev partials
// + runs the tiny LSTM (identical f32 math in all blocks), then computes its
// online-softmax partials with the fresh hs. Double-buffered partials (rd/wr).
__global__ __launch_bounds__(256) void k_s2s(
        const float* __restrict__ wih, const float* __restrict__ whh,
        const float* __restrict__ bih, const float* __restrict__ bhh,
        float* __restrict__ hs, float* __restrict__ cs,
        const float* __restrict__ out,
        const float* __restrict__ gmax_rd, const float* __restrict__ gsum_rd,
        const float* __restrict__ gr_rd,
        float* __restrict__ gmax_wr, float* __restrict__ gsum_wr,
        float* __restrict__ gr_wr, int it) {
    __shared__ float red[256], shs[64], scs[64], srv[64], sg[256];
    __shared__ float sm_m[4], sm_z[4], sm_r[4][64];
    int tid = threadIdx.x, lane = tid & 63, w = tid >> 6;

    if (it == 0) {
        if (tid < 64) { shs[tid] = 0.f; scs[tid] = 0.f; srv[tid] = 0.f; }
    } else {
        float gm = gmax_rd[tid];
        red[tid] = gm; __syncthreads();
        for (int s = 128; s > 0; s >>= 1) { if (tid < s) red[tid] = fmaxf(red[tid], red[tid+s]); __syncthreads(); }
        float M = red[0]; __syncthreads();
        red[tid] = gsum_rd[tid] * expf(gm - M); __syncthreads();
        for (int s = 128; s > 0; s >>= 1) { if (tid < s) red[tid] += red[tid+s]; __syncthreads(); }
        float Z = red[0]; __syncthreads();
        float racc = 0.f;
        for (int b = w; b < 256; b += 4) racc = fmaf(gr_rd[b*64 + lane], expf(gmax_rd[b] - M), racc);
        red[tid] = racc; __syncthreads();
        if (w == 0) srv[lane] = (red[lane] + red[64+lane] + red[128+lane] + red[192+lane]) / Z;
        if (tid < 64) { shs[tid] = hs[tid]; scs[tid] = cs[tid]; }
    }
    __syncthreads();

    // LSTM: g[tid] over 256 gates
    {
        const float* wi = wih + tid*128;
        const float* wh = whh + tid*64;
        float g = bih[tid] + bhh[tid];
        #pragma unroll 8
        for (int i = 0; i < 64; ++i) g += shs[i]*(wi[i] + wh[i]) + srv[i]*wi[64+i];
        sg[tid] = g;
    }
    __syncthreads();
    if (tid < 64) {
        float ii = sigf(sg[tid]), ff = sigf(sg[64+tid]);
        float gg = tanhf(sg[128+tid]), oo = sigf(sg[192+tid]);
        float c2 = ff*scs[tid] + ii*gg;
        float hn = oo*tanhf(c2);
        shs[tid] = hn;
        if (blockIdx.x == 0) { hs[tid] = hn; cs[tid] = c2; }
    }
    __syncthreads();

    // online-softmax partials with fresh hs
    float hsv = shs[lane];
    float m = -3.4e38f, Z2 = 0.f, racc2 = 0.f;
    for (int n = blockIdx.x*4 + w; n < Nn; n += 1024) {
        float ov = out[n*64 + lane];
        float p = ov * hsv;
        #pragma unroll
        for (int off = 32; off > 0; off >>= 1) p += __shfl_xor(p, off, 64);
        float mn = fmaxf(m, p);
        float sc = expf(m - mn);
        float t  = expf(p - mn);
        Z2 = fmaf(Z2, sc, t);
        racc2 = fmaf(racc2, sc, t*ov);
        m = mn;
    }
    if (lane == 0) { sm_m[w] = m; sm_z[w] = Z2; }
    sm_r[w][lane] = racc2;
    __syncthreads();
    if (w == 0) {
        float M = fmaxf(fmaxf(sm_m[0], sm_m[1]), fmaxf(sm_m[2], sm_m[3]));
        float Zb = 0.f, rb = 0.f;
        #pragma unroll
        for (int j = 0; j < 4; ++j) {
            float e = expf(sm_m[j] - M);
            Zb = fmaf(sm_z[j], e, Zb);
            rb = fmaf(sm_r[j][lane], e, rb);
        }
        gr_wr[blockIdx.x*64 + lane] = rb;
        if (lane == 0) { gmax_wr[blockIdx.x] = M; gsum_wr[blockIdx.x] = Zb; }
    }
}

// final: finalize rv, mem-LSTM (h=c=0), lin1, lin3 -> dout = [v, hx(64), cx(64)]
__global__ __launch_bounds__(256) void k_final2(const float* __restrict__ mwih,
        const float* __restrict__ mbih, const float* __restrict__ mbhh,
        const float* __restrict__ hs,
        const float* __restrict__ gmax, const float* __restrict__ gsum,
        const float* __restrict__ gr,
        const float* __restrict__ l1w, const float* __restrict__ l1b,
        const float* __restrict__ l3w, const float* __restrict__ l3b,
        float* __restrict__ dout) {
    __shared__ float red[256], shs[64], srv[64], sg[256], shx[64], so[64];
    int tid = threadIdx.x, lane = tid & 63, w = tid >> 6;
    {
        float gm = gmax[tid];
        red[tid] = gm; __syncthreads();
        for (int s = 128; s > 0; s >>= 1) { if (tid < s) red[tid] = fmaxf(red[tid], red[tid+s]); __syncthreads(); }
        float M = red[0]; __syncthreads();
        red[tid] = gsum[tid] * expf(gm - M); __syncthreads();
        for (int s = 128; s > 0; s >>= 1) { if (tid < s) red[tid] += red[tid+s]; __syncthreads(); }
        float Z = red[0]; __syncthreads();
        float racc = 0.f;
        for (int b = w; b < 256; b += 4) racc = fmaf(gr[b*64 + lane], expf(gmax[b] - M), racc);
        red[tid] = racc; __syncthreads();
        if (w == 0) srv[lane] = (red[lane] + red[64+lane] + red[128+lane] + red[192+lane]) / Z;
        if (tid < 64) shs[tid] = hs[tid];
    }
    __syncthreads();
    const float* wi = mwih + tid*128;
    float g = mbih[tid] + mbhh[tid];
    #pragma unroll 8
    for (int i = 0; i < 64; ++i) g += shs[i]*wi[i] + srv[i]*wi[64+i];
    sg[tid] = g; __syncthreads();
    if (tid < 64) {
        float ii = sigf(sg[tid]);
        float gg = tanhf(sg[128+tid]);
        float oo = sigf(sg[192+tid]);
        float c2 = ii * gg;
        float hx = oo * tanhf(c2);
        shx[tid] = hx;
        dout[1 + tid] = hx;
        dout[65 + tid] = c2;
    }
    __syncthreads();
    if (tid < 64) {
        float a = l1b[tid];
        const float* wr = l1w + tid*64;
        #pragma unroll 8
        for (int i = 0; i < 64; ++i) a = fmaf(shx[i], wr[i], a);
        so[tid] = fmaxf(a, 0.f);
    }
    __syncthreads();
    if (tid == 0) {
        float v = l3b[0];
        for (int i = 0; i < 64; ++i) v = fmaf(so[i], l3w[i], v);
        dout[0] = v;
    }
}

extern "C" void kernel_launch(void* const* d_in, const int* in_sizes, int n_in,
                              void* d_out, int out_size, void* d_ws, size_t ws_size,
                              hipStream_t stream) {
    const float* x    = (const float*)d_in[0];
    const int*   ei   = (const int*)  d_in[1];
    const float* ea   = (const float*)d_in[2];
    const float* l0w  = (const float*)d_in[3];
    const float* l0b  = (const float*)d_in[4];
    const float* e1w  = (const float*)d_in[5];
    const float* e1b  = (const float*)d_in[6];
    const float* e2w  = (const float*)d_in[7];
    const float* e2b  = (const float*)d_in[8];
    const float* rootw= (const float*)d_in[9];
    const float* convb= (const float*)d_in[10];
    const float* gwih = (const float*)d_in[11];
    const float* gwhh = (const float*)d_in[12];
    const float* gbih = (const float*)d_in[13];
    const float* gbhh = (const float*)d_in[14];
    const float* swih = (const float*)d_in[15];
    const float* swhh = (const float*)d_in[16];
    const float* sbih = (const float*)d_in[17];
    const float* sbhh = (const float*)d_in[18];
    const float* mwih = (const float*)d_in[19];
    const float* mbih = (const float*)d_in[21];
    const float* mbhh = (const float*)d_in[22];
    const float* l1w  = (const float*)d_in[23];
    const float* l1b  = (const float*)d_in[24];
    const float* l3w  = (const float*)d_in[25];
    const float* l3b  = (const float*)d_in[26];

    float* ws   = (float*)d_ws;
    float* dout = (float*)d_out;
    if (ws_size < (size_t)WS_FLOATS * sizeof(float)) return;

    float* agg  = ws + OFF_AGG;
    float* deg  = ws + OFF_DEG;
    float* out  = ws + OFF_OUT;
    float* dinv = ws + OFF_DINV;
    float* At   = ws + OFF_AT;
    float* Bt   = ws + OFF_BT;
    float* bp   = ws + OFF_BP;
    float* ubuf = ws + OFF_U;
    float* vbuf = ws + OFF_V;
    int*   mc   = (int*)(ws + OFF_MC);
    int*   pe   = (int*)(ws + OFF_PE);
    int*   bh   = (int*)(ws + OFF_BH);
    int*   bc   = (int*)(ws + OFF_BC);
    int*   sS   = (int*)(ws + OFF_SS);
    int*   sD   = (int*)(ws + OFF_SD);
    float* sA   = ws + OFF_SA;
    int*   sP   = (int*)(ws + OFF_SP);
    float* wAt  = ws + OFF_WAT;
    float* wBt  = ws + OFF_WBT;
    float* gmA  = ws + OFF_GMA;
    float* gsA  = ws + OFF_GSA;
    float* grA  = ws + OFF_GRA;
    float* gmB  = ws + OFF_GMB;
    float* gsB  = ws + OFF_GSB;
    float* grB  = ws + OFF_GRB;
    float* hs   = ws + OFF_HS;
    float* cs   = ws + OFF_CS;

    hipMemsetAsync(d_ws, 0, (size_t)ZERO_END * sizeof(float), stream);

    k_lin0    <<<(Nn*64 + 255)/256, 256, 0, stream>>>(x, l0w, l0b, out);
    k_patterns<<<1, 64, 0, stream>>>(e1w, e1b, bp, ubuf, vbuf, mc);
    k_AB      <<<65, 256, 0, stream>>>(e2w, e2b, ubuf, vbuf, mc, At, Bt);
    k_eprep2  <<<NB_E, 256, 0, stream>>>(ei, ea, bp, mc, deg, pe, bh);
    k_scan2   <<<60, 256, 0, stream>>>(deg, dinv, bh, bc);
    k_scatter2<<<NB_E, 256, 0, stream>>>(ei, ea, pe, bc, sS, sD, sA, sP);
    k_wt      <<<(16384 + 12288 + 255)/256, 256, 0, stream>>>(rootw, gwhh, gwih, wAt, wBt);

    for (int s = 0; s < 6; ++s) {
        k_edge3<<<EB, 256, 0, stream>>>(sS, sD, sA, sP, out, At, Bt, dinv, agg);
        k_gru2 <<<(Nn + TN - 1)/TN, 256, 0, stream>>>(out, agg, wAt, wBt, convb, gbih, gbhh);
    }

    for (int it = 0; it < 6; ++it) {
        float* gm_rd = (it & 1) ? gmA : gmB;   // unused at it=0
        float* gs_rd = (it & 1) ? gsA : gsB;
        float* gr_rd = (it & 1) ? grA : grB;
        float* gm_wr = (it & 1) ? gmB : gmA;
        float* gs_wr = (it & 1) ? gsB : gsA;
        float* gr_wr = (it & 1) ? grB : grA;
        k_s2s<<<256, 256, 0, stream>>>(swih, swhh, sbih, sbhh, hs, cs, out,
                                       gm_rd, gs_rd, gr_rd, gm_wr, gs_wr, gr_wr, it);
    }

    // it=5 wrote the B buffers
    k_final2<<<1, 256, 0, stream>>>(mwih, mbih, mbhh, hs, gmB, gsB, grB,
                                    l1w, l1b, l3w, l3b, dout);
}

// Round 4
// 677.212 us; speedup vs baseline: 1.4310x; 1.1754x over previous
//
#include <hip/hip_runtime.h>
#include <math.h>

#define Nn 15000
#define Ee 30000
#define NB_E 118   // ceil(Ee/256)
#define EB 768     // k_edge3 blocks

// ---- workspace layout (float offsets) ----
// zero region (memset each call):
#define OFF_AGG   0          // [Nn*64]
#define OFF_DEG   960000     // [Nn]
#define ZERO_END  975000
// written-before-read region:
#define OFF_OUT   975008     // [Nn*64]
#define OFF_DINV  1935008    // [Nn]
#define OFF_AT    1950016    // [65*4096] transposed: At[p][o*64+i]
#define OFF_BT    2216256    // [65*4096]
#define OFF_BP    2482496    // [64]
#define OFF_U     2482560    // [65*64]
#define OFF_V     2486720    // [65*64]
#define OFF_MC    2490880    // [1] int
#define OFF_PE    2490884    // [Ee] int
#define OFF_BH    2520884    // [NB_E*65] int per-block hist
#define OFF_BC    2528554    // [NB_E*65] int per-block cursors
#define OFF_SS    2536224    // [Ee] int
#define OFF_SD    2566224    // [Ee] int
#define OFF_SA    2596224    // [Ee] float
#define OFF_SP    2626224    // [Ee] int
#define OFF_WAT   2656224    // [64*256] wAt[i*256+o]: o<64 root, o>=64 whh^T gates
#define OFF_WBT   2672608    // [64*192] wBt[i*192+g]: wih^T gates
#define OFF_GMA   2684896    // [256]
#define OFF_GSA   2685152    // [256]
#define OFF_GRA   2685408    // [256*64]
#define OFF_GMB   2701792    // [256]
#define OFF_GSB   2702048    // [256]
#define OFF_GRB   2702304    // [256*64]
#define OFF_HS    2718688    // [64]
#define OFF_CS    2718752    // [64]
#define WS_FLOATS 2718816

__device__ __forceinline__ float sigf(float x) { return 1.0f / (1.0f + expf(-x)); }
__device__ __forceinline__ float bcast(float v, int l) {
    return __int_as_float(__builtin_amdgcn_readlane(__float_as_int(v), l));
}

__global__ void k_lin0(const float* __restrict__ x, const float* __restrict__ w,
                       const float* __restrict__ b, float* __restrict__ out) {
    int idx = blockIdx.x * 256 + threadIdx.x;
    if (idx >= Nn * 64) return;
    int n = idx >> 6, o = idx & 63;
    float v = b[o] + x[n*3+0]*w[o*3+0] + x[n*3+1]*w[o*3+1] + x[n*3+2]*w[o*3+2];
    out[idx] = fmaxf(v, 0.0f);
}

// he[e,k] = relu(a*w1[k]+b1[k]) piecewise-linear in scalar a: <=64 breakpoints.
__global__ void k_patterns(const float* __restrict__ e1w, const float* __restrict__ e1b,
                           float* __restrict__ bp, float* __restrict__ u,
                           float* __restrict__ v, int* __restrict__ mc) {
    __shared__ float t[64]; __shared__ int valid[64]; __shared__ float sbp[65]; __shared__ int cnt;
    int k = threadIdx.x;
    float w1 = e1w[k], b1 = e1b[k];
    float tv = 0.f; int va = 0;
    if (w1 != 0.f) { tv = -b1 / w1; va = (tv > 0.f && tv < 1.f) ? 1 : 0; }
    t[k] = tv; valid[k] = va;
    __syncthreads();
    if (va) {
        int rank = 0;
        for (int kk = 0; kk < 64; ++kk)
            if (valid[kk] && (t[kk] < tv || (t[kk] == tv && kk < k))) rank++;
        sbp[rank] = tv;
    }
    if (k == 0) { int c = 0; for (int kk = 0; kk < 64; ++kk) c += valid[kk]; cnt = c; *mc = c; }
    __syncthreads();
    int m = cnt;
    if (k < m) bp[k] = sbp[k];
    for (int j = 0; j <= m; ++j) {
        float lo = (j == 0) ? 0.f : sbp[j-1];
        float hi = (j == m) ? 1.f : sbp[j];
        float c = 0.5f * (lo + hi);
        int msk = (c * w1 + b1) > 0.f;
        u[j*64 + k] = msk ? w1 : 0.f;
        v[j*64 + k] = msk ? b1 : 0.f;
    }
}

// transposed outputs: At[j][o*64+i] = sum_k u_j[k]*e2w[(i*64+o)*64+k]; Bt likewise + e2b
__global__ void k_AB(const float* __restrict__ e2w, const float* __restrict__ e2b,
                     const float* __restrict__ u, const float* __restrict__ v,
                     const int* __restrict__ mc, float* __restrict__ At, float* __restrict__ Bt) {
    int j = blockIdx.x;
    if (j > *mc) return;
    __shared__ float su[64], sv[64];
    if (threadIdx.x < 64) { su[threadIdx.x] = u[j*64+threadIdx.x]; sv[threadIdx.x] = v[j*64+threadIdx.x]; }
    __syncthreads();
    for (int q = threadIdx.x; q < 4096; q += 256) {
        int i = q >> 6, o = q & 63;
        const float* row = e2w + q*64;
        float a = 0.f, b = 0.f;
        #pragma unroll 8
        for (int k = 0; k < 64; ++k) { float w = row[k]; a = fmaf(su[k], w, a); b = fmaf(sv[k], w, b); }
        At[j*4096 + o*64 + i] = a;
        Bt[j*4096 + o*64 + i] = b + e2b[q];
    }
}

// per-block LDS histogram (no global hist atomics) + deg + classify
__global__ void k_eprep2(const int* __restrict__ ei, const float* __restrict__ ea,
                         const float* __restrict__ bp, const int* __restrict__ mc,
                         float* __restrict__ deg, int* __restrict__ pe, int* __restrict__ bh) {
    __shared__ int lh[65];
    int tid = threadIdx.x;
    if (tid < 65) lh[tid] = 0;
    __syncthreads();
    int e = blockIdx.x * 256 + tid;
    if (e < Ee) {
        atomicAdd(&deg[ei[Ee + e]], 1.0f);
        float a = ea[e];
        int m = *mc, p = 0;
        for (int j = 0; j < m; ++j) p += (bp[j] <= a) ? 1 : 0;
        pe[e] = p;
        atomicAdd(&lh[p], 1);
    }
    __syncthreads();
    if (tid < 65) bh[blockIdx.x*65 + tid] = lh[tid];
}

// blocks 0..58: dinv; block 59: two-level scan -> per-block per-bin cursors
__global__ void k_scan2(const float* __restrict__ deg, float* __restrict__ dinv,
                        const int* __restrict__ bh, int* __restrict__ bc) {
    int tid = threadIdx.x;
    if (blockIdx.x < 59) {
        int n = blockIdx.x * 256 + tid;
        if (n < Nn) dinv[n] = 1.0f / fmaxf(deg[n], 1.0f);
        return;
    }
    __shared__ int stot[65]; __shared__ int sbase[65];
    if (tid < 65) {
        int t = 0;
        for (int b = 0; b < NB_E; ++b) t += bh[b*65 + tid];
        stot[tid] = t;
    }
    __syncthreads();
    if (tid == 0) {
        int run = 0;
        for (int j = 0; j < 65; ++j) { sbase[j] = run; run += stot[j]; }
    }
    __syncthreads();
    if (tid < 65) {
        int run = sbase[tid];
        for (int b = 0; b < NB_E; ++b) { bc[b*65 + tid] = run; run += bh[b*65 + tid]; }
    }
}

// scatter using per-block LDS cursors (LDS atomics only)
__global__ void k_scatter2(const int* __restrict__ ei, const float* __restrict__ ea,
                           const int* __restrict__ pe, const int* __restrict__ bc,
                           int* __restrict__ sS, int* __restrict__ sD,
                           float* __restrict__ sA, int* __restrict__ sP) {
    __shared__ int cur[65];
    int tid = threadIdx.x;
    if (tid < 65) cur[tid] = bc[blockIdx.x*65 + tid];
    __syncthreads();
    int e = blockIdx.x * 256 + tid;
    if (e >= Ee) return;
    int p = pe[e];
    int pos = atomicAdd(&cur[p], 1);
    sS[pos] = ei[e]; sD[pos] = ei[Ee + e]; sA[pos] = ea[e]; sP[pos] = p;
}

// transposed weight tables: wAt[i][0..63]=root_w[i][o]; wAt[i][64+g]=whh[g][i]; wBt[i][g]=wih[g][i]
__global__ void k_wt(const float* __restrict__ rootw, const float* __restrict__ whh,
                     const float* __restrict__ wih, float* __restrict__ wAt, float* __restrict__ wBt) {
    int idx = blockIdx.x * 256 + threadIdx.x;
    if (idx < 16384) {
        int i = idx >> 8, o = idx & 255;
        wAt[idx] = (o < 64) ? rootw[i*64 + o] : whh[(o-64)*64 + i];
    } else if (idx < 16384 + 12288) {
        int j = idx - 16384;
        int i = j / 192, g = j % 192;
        wBt[j] = wih[g*64 + i];
    }
}

// pattern-sorted edges, VGPR-cached pattern columns (float4 reload from transposed At/Bt)
__global__ __launch_bounds__(256) void k_edge3(
        const int* __restrict__ sS, const int* __restrict__ sD,
        const float* __restrict__ sA, const int* __restrict__ sP,
        const float* __restrict__ out, const float* __restrict__ At,
        const float* __restrict__ Bt, const float* __restrict__ dinv,
        float* __restrict__ agg) {
    int tid = threadIdx.x, lane = tid & 63;
    int wid = (blockIdx.x * 256 + tid) >> 6;       // 0..EB*4-1
    const int NW = EB * 4;
    const int CH = (Ee + NW - 1) / NW;
    int e0 = wid * CH;
    int e1 = e0 + CH; if (e1 > Ee) e1 = Ee;
    float Ar[64], Br[64];
    int curp = -1;
    for (int e = e0; e < e1; ++e) {
        int p = sP[e];
        if (p != curp) {
            curp = p;
            const float4* Ap4 = (const float4*)(At + p*4096 + lane*64);
            const float4* Bp4 = (const float4*)(Bt + p*4096 + lane*64);
            #pragma unroll
            for (int q = 0; q < 16; ++q) {
                float4 av = Ap4[q], bv = Bp4[q];
                Ar[q*4+0]=av.x; Ar[q*4+1]=av.y; Ar[q*4+2]=av.z; Ar[q*4+3]=av.w;
                Br[q*4+0]=bv.x; Br[q*4+1]=bv.y; Br[q*4+2]=bv.z; Br[q*4+3]=bv.w;
            }
        }
        int src = sS[e], dst = sD[e];
        float a = sA[e];
        float hv = out[src*64 + lane];
        float acc0 = 0.f, acc1 = 0.f;
        #pragma unroll
        for (int i = 0; i < 64; i += 2) {
            float h0 = bcast(hv, i);
            float h1 = bcast(hv, i+1);
            acc0 = fmaf(h0, fmaf(a, Ar[i],   Br[i]),   acc0);
            acc1 = fmaf(h1, fmaf(a, Ar[i+1], Br[i+1]), acc1);
        }
        float acc = (acc0 + acc1) * dinv[dst];
        atomicAdd(&agg[dst*64 + lane], acc);
    }
}

// fused NNConv-root + full GRU. lane = node (64-node tile), wave wu owns a
// 16-output-column chunk of every gate. h/m reads: lane-varying conflict-free
// ds_read_b32 (stride 65). Weight reads: wave-uniform -> SGPR s_load (free).
// 7168 FMA/thread, 96 static accumulators -> VALU-bound.
__global__ __launch_bounds__(256, 1) void k_gru3(
        float* __restrict__ out, float* __restrict__ agg,
        const float* __restrict__ wAt, const float* __restrict__ wBt,
        const float* __restrict__ convb, const float* __restrict__ gbih,
        const float* __restrict__ gbhh) {
    __shared__ float hT[64*65];   // hT[i*65+n] = h[n][i]
    __shared__ float mT[64*65];
    __shared__ float xT[64*65];   // aggT, then reused as outT
    int tid = threadIdx.x;
    int lane = tid & 63;
    int wu = __builtin_amdgcn_readfirstlane(tid >> 6);
    int n0 = blockIdx.x * 64;
    const int base = n0 * 64;
    const int ob = wu * 16;

    // stage h, agg transposed; zero agg (all coalesced)
    #pragma unroll
    for (int p = 0; p < 16; ++p) {
        int idx = p*256 + tid;
        int g = base + idx;
        int n = idx >> 6, i = idx & 63;
        float hvv = 0.f, avv = 0.f;
        if (g < Nn*64) {
            hvv = out[g];
            avv = agg[g];
            agg[g] = 0.f;
        }
        hT[i*65 + n] = hvv;
        xT[i*65 + n] = avv;
    }
    __syncthreads();

    // ---- phase 1a: root matvec ----
    float rt[16];
    #pragma unroll
    for (int j = 0; j < 16; ++j) rt[j] = 0.f;
    for (int i = 0; i < 64; ++i) {
        float hv = hT[i*65 + lane];
        const float* wr = wAt + i*256 + ob;       // uniform -> s_load
        #pragma unroll
        for (int j = 0; j < 16; ++j) rt[j] = fmaf(hv, wr[j], rt[j]);
    }
    // m = relu(root + agg + convb) -> mT (this wave's 16 rows)
    #pragma unroll
    for (int j = 0; j < 16; ++j) {
        float mvv = fmaxf(rt[j] + xT[(ob+j)*65 + lane] + convb[ob+j], 0.f);
        mT[(ob+j)*65 + lane] = mvv;
    }

    // ---- phase 1b: gh gates (read hT) ----
    float ghr[16], ghz[16], ghn[16];
    #pragma unroll
    for (int j = 0; j < 16; ++j) {
        ghr[j] = gbhh[ob+j]; ghz[j] = gbhh[64+ob+j]; ghn[j] = gbhh[128+ob+j];
    }
    for (int i = 0; i < 64; ++i) {
        float hv = hT[i*65 + lane];
        const float* wr = wAt + i*256 + 64 + ob;  // uniform -> s_load
        #pragma unroll
        for (int j = 0; j < 16; ++j) ghr[j] = fmaf(hv, wr[j], ghr[j]);
        #pragma unroll
        for (int j = 0; j < 16; ++j) ghz[j] = fmaf(hv, wr[64+j], ghz[j]);
        #pragma unroll
        for (int j = 0; j < 16; ++j) ghn[j] = fmaf(hv, wr[128+j], ghn[j]);
    }
    __syncthreads();   // mT complete

    // ---- phase 2: gi gates (read mT) ----
    float gir[16], giz[16], gin[16];
    #pragma unroll
    for (int j = 0; j < 16; ++j) {
        gir[j] = gbih[ob+j]; giz[j] = gbih[64+ob+j]; gin[j] = gbih[128+ob+j];
    }
    for (int i = 0; i < 64; ++i) {
        float mv = mT[i*65 + lane];
        const float* wr = wBt + i*192 + ob;       // uniform -> s_load
        #pragma unroll
        for (int j = 0; j < 16; ++j) gir[j] = fmaf(mv, wr[j], gir[j]);
        #pragma unroll
        for (int j = 0; j < 16; ++j) giz[j] = fmaf(mv, wr[64+j], giz[j]);
        #pragma unroll
        for (int j = 0; j < 16; ++j) gin[j] = fmaf(mv, wr[128+j], gin[j]);
    }

    // ---- phase 3: combine (all in regs), stage to xT, coalesced write ----
    #pragma unroll
    for (int j = 0; j < 16; ++j) {
        float r  = sigf(gir[j] + ghr[j]);
        float z  = sigf(giz[j] + ghz[j]);
        float nn = tanhf(fmaf(r, ghn[j], gin[j]));
        float h  = hT[(ob+j)*65 + lane];
        xT[(ob+j)*65 + lane] = (1.f - z)*nn + z*h;
    }
    __syncthreads();
    #pragma unroll
    for (int p = 0; p < 16; ++p) {
        int idx = p*256 + tid;
        int g = base + idx;
        if (g < Nn*64) out[g] = xT[(idx & 63)*65 + (idx >> 6)];
    }
}

// one launch per Set2Set iteration: every block redundantly finalizes prev partials
// + runs the tiny LSTM (identical f32 math in all blocks), then computes its
// online-softmax partials with the fresh hs. Double-buffered partials (rd/wr).
__global__ __launch_bounds__(256) void k_s2s(
        const float* __restrict__ wih, const float* __restrict__ whh,
        const float* __restrict__ bih, const float* __restrict__ bhh,
        float* __restrict__ hs, float* __restrict__ cs,
        const float* __restrict__ out,
        const float* __restrict__ gmax_rd, const float* __restrict__ gsum_rd,
        const float* __restrict__ gr_rd,
        float* __restrict__ gmax_wr, float* __restrict__ gsum_wr,
        float* __restrict__ gr_wr, int it) {
    __shared__ float red[256], shs[64], scs[64], srv[64], sg[256];
    __shared__ float sm_m[4], sm_z[4], sm_r[4][64];
    int tid = threadIdx.x, lane = tid & 63, w = tid >> 6;

    if (it == 0) {
        if (tid < 64) { shs[tid] = 0.f; scs[tid] = 0.f; srv[tid] = 0.f; }
    } else {
        float gm = gmax_rd[tid];
        red[tid] = gm; __syncthreads();
        for (int s = 128; s > 0; s >>= 1) { if (tid < s) red[tid] = fmaxf(red[tid], red[tid+s]); __syncthreads(); }
        float M = red[0]; __syncthreads();
        red[tid] = gsum_rd[tid] * expf(gm - M); __syncthreads();
        for (int s = 128; s > 0; s >>= 1) { if (tid < s) red[tid] += red[tid+s]; __syncthreads(); }
        float Z = red[0]; __syncthreads();
        float racc = 0.f;
        for (int b = w; b < 256; b += 4) racc = fmaf(gr_rd[b*64 + lane], expf(gmax_rd[b] - M), racc);
        red[tid] = racc; __syncthreads();
        if (w == 0) srv[lane] = (red[lane] + red[64+lane] + red[128+lane] + red[192+lane]) / Z;
        if (tid < 64) { shs[tid] = hs[tid]; scs[tid] = cs[tid]; }
    }
    __syncthreads();

    // LSTM: g[tid] over 256 gates
    {
        const float* wi = wih + tid*128;
        const float* wh = whh + tid*64;
        float g = bih[tid] + bhh[tid];
        #pragma unroll 8
        for (int i = 0; i < 64; ++i) g += shs[i]*(wi[i] + wh[i]) + srv[i]*wi[64+i];
        sg[tid] = g;
    }
    __syncthreads();
    if (tid < 64) {
        float ii = sigf(sg[tid]), ff = sigf(sg[64+tid]);
        float gg = tanhf(sg[128+tid]), oo = sigf(sg[192+tid]);
        float c2 = ff*scs[tid] + ii*gg;
        float hn = oo*tanhf(c2);
        shs[tid] = hn;
        if (blockIdx.x == 0) { hs[tid] = hn; cs[tid] = c2; }
    }
    __syncthreads();

    // online-softmax partials with fresh hs
    float hsv = shs[lane];
    float m = -3.4e38f, Z2 = 0.f, racc2 = 0.f;
    for (int n = blockIdx.x*4 + w; n < Nn; n += 1024) {
        float ov = out[n*64 + lane];
        float p = ov * hsv;
        #pragma unroll
        for (int off = 32; off > 0; off >>= 1) p += __shfl_xor(p, off, 64);
        float mn = fmaxf(m, p);
        float sc = expf(m - mn);
        float t  = expf(p - mn);
        Z2 = fmaf(Z2, sc, t);
        racc2 = fmaf(racc2, sc, t*ov);
        m = mn;
    }
    if (lane == 0) { sm_m[w] = m; sm_z[w] = Z2; }
    sm_r[w][lane] = racc2;
    __syncthreads();
    if (w == 0) {
        float M = fmaxf(fmaxf(sm_m[0], sm_m[1]), fmaxf(sm_m[2], sm_m[3]));
        float Zb = 0.f, rb = 0.f;
        #pragma unroll
        for (int j = 0; j < 4; ++j) {
            float e = expf(sm_m[j] - M);
            Zb = fmaf(sm_z[j], e, Zb);
            rb = fmaf(sm_r[j][lane], e, rb);
        }
        gr_wr[blockIdx.x*64 + lane] = rb;
        if (lane == 0) { gmax_wr[blockIdx.x] = M; gsum_wr[blockIdx.x] = Zb; }
    }
}

// final: finalize rv, mem-LSTM (h=c=0), lin1, lin3 -> dout = [v, hx(64), cx(64)]
__global__ __launch_bounds__(256) void k_final2(const float* __restrict__ mwih,
        const float* __restrict__ mbih, const float* __restrict__ mbhh,
        const float* __restrict__ hs,
        const float* __restrict__ gmax, const float* __restrict__ gsum,
        const float* __restrict__ gr,
        const float* __restrict__ l1w, const float* __restrict__ l1b,
        const float* __restrict__ l3w, const float* __restrict__ l3b,
        float* __restrict__ dout) {
    __shared__ float red[256], shs[64], srv[64], sg[256], shx[64], so[64];
    int tid = threadIdx.x, lane = tid & 63, w = tid >> 6;
    {
        float gm = gmax[tid];
        red[tid] = gm; __syncthreads();
        for (int s = 128; s > 0; s >>= 1) { if (tid < s) red[tid] = fmaxf(red[tid], red[tid+s]); __syncthreads(); }
        float M = red[0]; __syncthreads();
        red[tid] = gsum[tid] * expf(gm - M); __syncthreads();
        for (int s = 128; s > 0; s >>= 1) { if (tid < s) red[tid] += red[tid+s]; __syncthreads(); }
        float Z = red[0]; __syncthreads();
        float racc = 0.f;
        for (int b = w; b < 256; b += 4) racc = fmaf(gr[b*64 + lane], expf(gmax[b] - M), racc);
        red[tid] = racc; __syncthreads();
        if (w == 0) srv[lane] = (red[lane] + red[64+lane] + red[128+lane] + red[192+lane]) / Z;
        if (tid < 64) shs[tid] = hs[tid];
    }
    __syncthreads();
    const float* wi = mwih + tid*128;
    float g = mbih[tid] + mbhh[tid];
    #pragma unroll 8
    for (int i = 0; i < 64; ++i) g += shs[i]*wi[i] + srv[i]*wi[64+i];
    sg[tid] = g; __syncthreads();
    if (tid < 64) {
        float ii = sigf(sg[tid]);
        float gg = tanhf(sg[128+tid]);
        float oo = sigf(sg[192+tid]);
        float c2 = ii * gg;
        float hx = oo * tanhf(c2);
        shx[tid] = hx;
        dout[1 + tid] = hx;
        dout[65 + tid] = c2;
    }
    __syncthreads();
    if (tid < 64) {
        float a = l1b[tid];
        const float* wr = l1w + tid*64;
        #pragma unroll 8
        for (int i = 0; i < 64; ++i) a = fmaf(shx[i], wr[i], a);
        so[tid] = fmaxf(a, 0.f);
    }
    __syncthreads();
    if (tid == 0) {
        float v = l3b[0];
        for (int i = 0; i < 64; ++i) v = fmaf(so[i], l3w[i], v);
        dout[0] = v;
    }
}

extern "C" void kernel_launch(void* const* d_in, const int* in_sizes, int n_in,
                              void* d_out, int out_size, void* d_ws, size_t ws_size,
                              hipStream_t stream) {
    const float* x    = (const float*)d_in[0];
    const int*   ei   = (const int*)  d_in[1];
    const float* ea   = (const float*)d_in[2];
    const float* l0w  = (const float*)d_in[3];
    const float* l0b  = (const float*)d_in[4];
    const float* e1w  = (const float*)d_in[5];
    const float* e1b  = (const float*)d_in[6];
    const float* e2w  = (const float*)d_in[7];
    const float* e2b  = (const float*)d_in[8];
    const float* rootw= (const float*)d_in[9];
    const float* convb= (const float*)d_in[10];
    const float* gwih = (const float*)d_in[11];
    const float* gwhh = (const float*)d_in[12];
    const float* gbih = (const float*)d_in[13];
    const float* gbhh = (const float*)d_in[14];
    const float* swih = (const float*)d_in[15];
    const float* swhh = (const float*)d_in[16];
    const float* sbih = (const float*)d_in[17];
    const float* sbhh = (const float*)d_in[18];
    const float* mwih = (const float*)d_in[19];
    const float* mbih = (const float*)d_in[21];
    const float* mbhh = (const float*)d_in[22];
    const float* l1w  = (const float*)d_in[23];
    const float* l1b  = (const float*)d_in[24];
    const float* l3w  = (const float*)d_in[25];
    const float* l3b  = (const float*)d_in[26];

    float* ws   = (float*)d_ws;
    float* dout = (float*)d_out;
    if (ws_size < (size_t)WS_FLOATS * sizeof(float)) return;

    float* agg  = ws + OFF_AGG;
    float* deg  = ws + OFF_DEG;
    float* out  = ws + OFF_OUT;
    float* dinv = ws + OFF_DINV;
    float* At   = ws + OFF_AT;
    float* Bt   = ws + OFF_BT;
    float* bp   = ws + OFF_BP;
    float* ubuf = ws + OFF_U;
    float* vbuf = ws + OFF_V;
    int*   mc   = (int*)(ws + OFF_MC);
    int*   pe   = (int*)(ws + OFF_PE);
    int*   bh   = (int*)(ws + OFF_BH);
    int*   bc   = (int*)(ws + OFF_BC);
    int*   sS   = (int*)(ws + OFF_SS);
    int*   sD   = (int*)(ws + OFF_SD);
    float* sA   = ws + OFF_SA;
    int*   sP   = (int*)(ws + OFF_SP);
    float* wAt  = ws + OFF_WAT;
    float* wBt  = ws + OFF_WBT;
    float* gmA  = ws + OFF_GMA;
    float* gsA  = ws + OFF_GSA;
    float* grA  = ws + OFF_GRA;
    float* gmB  = ws + OFF_GMB;
    float* gsB  = ws + OFF_GSB;
    float* grB  = ws + OFF_GRB;
    float* hs   = ws + OFF_HS;
    float* cs   = ws + OFF_CS;

    hipMemsetAsync(d_ws, 0, (size_t)ZERO_END * sizeof(float), stream);

    k_lin0    <<<(Nn*64 + 255)/256, 256, 0, stream>>>(x, l0w, l0b, out);
    k_patterns<<<1, 64, 0, stream>>>(e1w, e1b, bp, ubuf, vbuf, mc);
    k_AB      <<<65, 256, 0, stream>>>(e2w, e2b, ubuf, vbuf, mc, At, Bt);
    k_eprep2  <<<NB_E, 256, 0, stream>>>(ei, ea, bp, mc, deg, pe, bh);
    k_scan2   <<<60, 256, 0, stream>>>(deg, dinv, bh, bc);
    k_scatter2<<<NB_E, 256, 0, stream>>>(ei, ea, pe, bc, sS, sD, sA, sP);
    k_wt      <<<(16384 + 12288 + 255)/256, 256, 0, stream>>>(rootw, gwhh, gwih, wAt, wBt);

    for (int s = 0; s < 6; ++s) {
        k_edge3<<<EB, 256, 0, stream>>>(sS, sD, sA, sP, out, At, Bt, dinv, agg);
        k_gru3 <<<(Nn + 63)/64, 256, 0, stream>>>(out, agg, wAt, wBt, convb, gbih, gbhh);
    }

    for (int it = 0; it < 6; ++it) {
        float* gm_rd = (it & 1) ? gmA : gmB;   // unused at it=0
        float* gs_rd = (it & 1) ? gsA : gsB;
        float* gr_rd = (it & 1) ? grA : grB;
        float* gm_wr = (it & 1) ? gmB : gmA;
        float* gs_wr = (it & 1) ? gsB : gsA;
        float* gr_wr = (it & 1) ? grB : grA;
        k_s2s<<<256, 256, 0, stream>>>(swih, swhh, sbih, sbhh, hs, cs, out,
                                       gm_rd, gs_rd, gr_rd, gm_wr, gs_wr, gr_wr, it);
    }

    // it=5 wrote the B buffers
    k_final2<<<1, 256, 0, stream>>>(mwih, mbih, mbhh, hs, gmB, gsB, grB,
                                    l1w, l1b, l3w, l3b, dout);
}